// Round 5
// baseline (608.655 us; speedup 1.0000x reference)
//
#include <hip/hip_runtime.h>
#include <hip/hip_cooperative_groups.h>
#include <math.h>

namespace cg = cooperative_groups;

#define NFEAT 128
#define NHID 256
#define NBLK 256  // partition blocks == k_build grid

typedef __attribute__((ext_vector_type(8))) short short8;
typedef __attribute__((ext_vector_type(4))) float f32x4;
typedef __attribute__((ext_vector_type(2))) float f32x2;

__device__ inline unsigned short f2bf(float f) {
  unsigned u = __float_as_uint(f);
  u += 0x7fffu + ((u >> 16) & 1u);
  return (unsigned short)(u >> 16);
}
__device__ inline float bflo(unsigned u) { return __uint_as_float(u << 16); }
__device__ inline float bfhi(unsigned u) { return __uint_as_float(u & 0xffff0000u); }

// ---- W pack helper: bf16 B-fragment layout for 16x16x32 MFMA ----
__device__ inline void packOne(const float* __restrict__ W,
                               unsigned short* __restrict__ Wp, int idx, int KS,
                               int OUT) {
  int lane = idx & 63;
  int t = idx >> 6;
  int ks = t % KS;
  int nt = t / KS;
  int n = nt * 16 + (lane & 15);
  int k0 = ks * 32 + (lane >> 4) * 8;
  unsigned short v[8];
#pragma unroll
  for (int j = 0; j < 8; j++) v[j] = f2bf(W[(size_t)(k0 + j) * OUT + n]);
  *reinterpret_cast<short8*>(Wp + (size_t)idx * 8) =
      *reinterpret_cast<short8*>(v);
}

// ================= ONE-SHOT cooperative CSR build ==========================
// 256 blocks x 1024 threads, 4 grid syncs:
//  ph1 hist (LDS) + W-pack + Cbuf -> ph2 per-bucket row prefix (relative) +
//  bucket totals -> ph3 bucket-total scan (block 0) -> ph5 partition ->
//  ph6 per-bucket counting sort + offs/dinv + feat->bf16 cvt.
__global__ __launch_bounds__(1024) void k_build(
    const int* __restrict__ col, const int* __restrict__ row,
    int* __restrict__ hist2d, int* __restrict__ sbase, int* __restrict__ T,
    int* __restrict__ B, unsigned* __restrict__ tmp, int* __restrict__ ebuf,
    int* __restrict__ offs, float* __restrict__ dinv,
    const float* __restrict__ feat, unsigned short* __restrict__ xs,
    const float* __restrict__ W1, const float* __restrict__ W2,
    unsigned short* __restrict__ W1p, unsigned short* __restrict__ W2p,
    const float* __restrict__ b2, const float* __restrict__ Wl,
    const float* __restrict__ bl, float* __restrict__ Cbuf, int nE, int n,
    int nb) {
  cg::grid_group grid = cg::this_grid();
  __shared__ int smi[2048];
  __shared__ float sdinv[64];
  int t = threadIdx.x;
  int b = blockIdx.x;
  int chunk = (nE + NBLK - 1) / NBLK;
  int ebeg = b * chunk, eend = min(ebeg + chunk, nE);

  // ---- phase 1: histogram (+ W pack on blocks 0..7, Cbuf on block 255) ----
  for (int i = t; i < nb; i += 1024) smi[i] = 0;
  __syncthreads();
  for (int e = ebeg + t; e < eend; e += 1024) atomicAdd(&smi[col[e] >> 6], 1);
  if (b < 8) {
    int idx = b * 1024 + t;
    if (idx < 4096) packOne(W1, W1p, idx, 4, 256);
    else packOne(W2, W2p, idx - 4096, 8, 128);
  }
  if (b == 255) {  // C = b2.(Wl_lo+Wl_hi) + bl
    float v = (t < 128) ? b2[t] * (Wl[t] + Wl[128 + t]) : 0.f;
#pragma unroll
    for (int o = 32; o; o >>= 1) v += __shfl_down(v, o);
    if (t == 0) sdinv[0] = v;
    if (t == 64) sdinv[1] = v;
    __syncthreads();
    if (t == 0) Cbuf[0] = sdinv[0] + sdinv[1] + bl[0];
  }
  __syncthreads();
  for (int i = t; i < nb; i += 1024) hist2d[i * NBLK + b] = smi[i];
  __threadfence();
  grid.sync();

  // ---- phase 2: per-bucket row prefix (4 buckets/block, 256 thr each) ----
  {
    int sub = t >> 8, tc = t & 255;
    int bkt = b * 4 + sub;
    int v = (bkt < nb) ? hist2d[bkt * NBLK + tc] : 0;
    smi[sub * 256 + tc] = v;
    __syncthreads();
    for (int o = 1; o < 256; o <<= 1) {
      int u = (tc >= o) ? smi[sub * 256 + tc - o] : 0;
      __syncthreads();
      smi[sub * 256 + tc] += u;
      __syncthreads();
    }
    if (bkt < nb) {
      sbase[bkt * NBLK + tc] = smi[sub * 256 + tc] - v;  // exclusive, relative
      if (tc == 255) T[bkt] = smi[sub * 256 + 255];
    }
  }
  __threadfence();
  grid.sync();

  // ---- phase 3: exclusive scan of bucket totals (block 0 only) ----
  if (b == 0) {
    int v = (t < nb) ? T[t] : 0;
    smi[t] = v;
    __syncthreads();
    for (int o = 1; o < 1024; o <<= 1) {
      int u = (t >= o) ? smi[t - o] : 0;
      __syncthreads();
      smi[t] += u;
      __syncthreads();
    }
    if (t < nb) B[t] = smi[t] - v;
    __threadfence();
  }
  grid.sync();

  // ---- phase 5: partition edges into per-(bucket,block) segments ----
  for (int i = t; i < nb; i += 1024) smi[i] = sbase[i * NBLK + b] + B[i];
  __syncthreads();
  for (int e = ebeg + t; e < eend; e += 1024) {
    int c = col[e];
    int pos = atomicAdd(&smi[c >> 6], 1);
    tmp[pos] = ((unsigned)(c & 63) << 16) | (unsigned)row[e];
  }
  __threadfence();
  grid.sync();

  // ---- phase 6: per-bucket counting sort + offs/dinv + cvt ----
  if (b == 0 && t == 0) offs[n] = nE;
  int w16 = t >> 6;
  for (int bk = b; bk < nb; bk += NBLK) {
    int sbeg = B[bk] + sbase[bk * NBLK];
    int send = (bk == nb - 1) ? nE : (B[bk + 1] + sbase[(bk + 1) * NBLK]);
    smi[t] = 0;
    smi[1024 + t] = 0;  // bins = smi[0..1023] [16][64], cur16 = smi[1024..]
    __syncthreads();
    for (int i = sbeg + t; i < send; i += 1024)
      atomicAdd(&smi[w16 * 64 + (tmp[i] >> 16)], 1);
    __syncthreads();
    if (t < 64) {
      int tot = 0;
#pragma unroll
      for (int j = 0; j < 16; j++) tot += smi[j * 64 + t];
      int s = tot;
#pragma unroll
      for (int o = 1; o < 64; o <<= 1) {
        int u = __shfl_up(s, o);
        if (t >= o) s += u;
      }
      int off = sbeg + s - tot;
      int run = off;
#pragma unroll
      for (int j = 0; j < 16; j++) {
        smi[1024 + j * 64 + t] = run;
        run += smi[j * 64 + t];
      }
      float dv = rsqrtf((float)(tot + 1));  // +1 self loop
      sdinv[t] = dv;
      int node = bk * 64 + t;
      if (node < n) {
        offs[node] = off;
        dinv[node] = dv;
      }
    }
    __syncthreads();
    for (int i = sbeg + t; i < send; i += 1024) {
      unsigned p = tmp[i];
      int pos = atomicAdd(&smi[1024 + w16 * 64 + (p >> 16)], 1);
      ebuf[pos] = (int)(p & 0xffffu);
    }
    for (int i = t; i < 2048; i += 1024) {  // cvt: 64 rows x 32 float4
      int r = i >> 5;
      int node = bk * 64 + r;
      if (node < n) {
        float d = sdinv[r];
        float4 v =
            reinterpret_cast<const float4*>(feat)[(size_t)node * 32 + (i & 31)];
        unsigned short o[4] = {f2bf(v.x * d), f2bf(v.y * d), f2bf(v.z * d),
                               f2bf(v.w * d)};
        reinterpret_cast<ushort4*>(xs)[(size_t)node * 32 + (i & 31)] =
            *reinterpret_cast<ushort4*>(o);
      }
    }
    __syncthreads();
  }
}

// ============ Fallback chain (used only if cooperative launch fails) ========
__global__ __launch_bounds__(1024) void k_hist_pack(
    const int* __restrict__ col, int* __restrict__ hist2d, int nE, int nb,
    const float* __restrict__ W1, const float* __restrict__ W2,
    unsigned short* __restrict__ W1p, unsigned short* __restrict__ W2p) {
  if (blockIdx.x >= NBLK) {
    int idx = (blockIdx.x - NBLK) * 1024 + threadIdx.x;
    if (idx < 4096) packOne(W1, W1p, idx, 4, 256);
    else packOne(W2, W2p, idx - 4096, 8, 128);
    return;
  }
  __shared__ int h[1024];
  for (int i = threadIdx.x; i < nb; i += 1024) h[i] = 0;
  __syncthreads();
  int chunk = (nE + NBLK - 1) / NBLK;
  int beg = blockIdx.x * chunk, end = min(beg + chunk, nE);
  for (int e = beg + threadIdx.x; e < end; e += 1024)
    atomicAdd(&h[col[e] >> 6], 1);
  __syncthreads();
  for (int i = threadIdx.x; i < nb; i += 1024)
    hist2d[i * NBLK + blockIdx.x] = h[i];
}

__global__ __launch_bounds__(256) void k_bsum(const int* __restrict__ a,
                                              int* __restrict__ psum, int S,
                                              const float* __restrict__ b2,
                                              const float* __restrict__ Wl,
                                              const float* __restrict__ bl,
                                              float* __restrict__ Cbuf) {
  int t = threadIdx.x;
  if (blockIdx.x == gridDim.x - 1) {
    float v = (t < 128) ? b2[t] * (Wl[t] + Wl[128 + t]) : 0.f;
#pragma unroll
    for (int o = 32; o; o >>= 1) v += __shfl_down(v, o);
    __shared__ float fw[4];
    if ((t & 63) == 0) fw[t >> 6] = v;
    __syncthreads();
    if (t == 0) Cbuf[0] = fw[0] + fw[1] + fw[2] + fw[3] + bl[0];
    return;
  }
  int i = blockIdx.x * 256 + t;
  int v = (i < S) ? a[i] : 0;
#pragma unroll
  for (int o = 32; o; o >>= 1) v += __shfl_down(v, o);
  __shared__ int ws[4];
  if ((t & 63) == 0) ws[t >> 6] = v;
  __syncthreads();
  if (t == 0) psum[blockIdx.x] = ws[0] + ws[1] + ws[2] + ws[3];
}

__global__ __launch_bounds__(256) void k_s3m(const int* __restrict__ a,
                                             const int* __restrict__ psum,
                                             int* __restrict__ out, int S) {
  __shared__ int sh[256];
  __shared__ int ws[4];
  int t = threadIdx.x;
  int b = blockIdx.x;
  int partial = 0;
  for (int i = t; i < b; i += 256) partial += psum[i];
#pragma unroll
  for (int o = 32; o; o >>= 1) partial += __shfl_down(partial, o);
  if ((t & 63) == 0) ws[t >> 6] = partial;
  int i = b * 256 + t;
  int d = (i < S) ? a[i] : 0;
  sh[t] = d;
  __syncthreads();
  int base = ws[0] + ws[1] + ws[2] + ws[3];
  for (int o = 1; o < 256; o <<= 1) {
    int u = (t >= o) ? sh[t - o] : 0;
    __syncthreads();
    sh[t] += u;
    __syncthreads();
  }
  if (i < S) out[i] = base + sh[t] - d;
}

__global__ __launch_bounds__(1024) void k_part2(const int* __restrict__ row,
                                                const int* __restrict__ col,
                                                const int* __restrict__ sbase,
                                                unsigned* __restrict__ tmp,
                                                int nE, int nb) {
  __shared__ int cur[1024];
  for (int i = threadIdx.x; i < nb; i += 1024)
    cur[i] = sbase[i * NBLK + blockIdx.x];
  __syncthreads();
  int chunk = (nE + NBLK - 1) / NBLK;
  int beg = blockIdx.x * chunk, end = min(beg + chunk, nE);
  for (int e = beg + threadIdx.x; e < end; e += 1024) {
    int c = col[e];
    int pos = atomicAdd(&cur[c >> 6], 1);
    tmp[pos] = ((unsigned)(c & 63) << 16) | (unsigned)row[e];
  }
}

__global__ __launch_bounds__(256) void k_bsort_cvt(
    const unsigned* __restrict__ tmp, const int* __restrict__ sbase,
    int* __restrict__ ebuf, int* __restrict__ offs, float* __restrict__ dinv,
    const float* __restrict__ feat, unsigned short* __restrict__ xs, int n,
    int nE, int nb) {
  __shared__ int bins[4][64], cur4[4][64];
  __shared__ float sdinv[64];
  int b = blockIdx.x;
  int beg = sbase[b * NBLK];
  int end = (b == nb - 1) ? nE : sbase[(b + 1) * NBLK];
  int t = threadIdx.x;
  int w4 = t >> 6;
  if (t == 0 && b == nb - 1) offs[n] = nE;
  bins[w4][t & 63] = 0;
  __syncthreads();
  for (int i = beg + t; i < end; i += 256)
    atomicAdd(&bins[w4][tmp[i] >> 16], 1);
  __syncthreads();
  if (t < 64) {
    int b0 = bins[0][t], b1 = bins[1][t], b2 = bins[2][t], b3 = bins[3][t];
    int v = b0 + b1 + b2 + b3;
    int s = v;
#pragma unroll
    for (int o = 1; o < 64; o <<= 1) {
      int u = __shfl_up(s, o);
      if (t >= o) s += u;
    }
    int off = beg + s - v;
    cur4[0][t] = off;
    cur4[1][t] = off + b0;
    cur4[2][t] = off + b0 + b1;
    cur4[3][t] = off + b0 + b1 + b2;
    float dv = rsqrtf((float)(v + 1));
    sdinv[t] = dv;
    int node = b * 64 + t;
    if (node < n) {
      offs[node] = off;
      dinv[node] = dv;
    }
  }
  __syncthreads();
  for (int i = beg + t; i < end; i += 256) {
    unsigned p = tmp[i];
    int pos = atomicAdd(&cur4[w4][p >> 16], 1);
    ebuf[pos] = (int)(p & 0xffffu);
  }
  for (int i = t; i < 64 * 32; i += 256) {
    int r = i >> 5;
    int node = b * 64 + r;
    if (node >= n) break;
    float d = sdinv[r];
    float4 v = reinterpret_cast<const float4*>(feat)[(size_t)node * 32 + (i & 31)];
    unsigned short o[4] = {f2bf(v.x * d), f2bf(v.y * d), f2bf(v.z * d),
                           f2bf(v.w * d)};
    reinterpret_cast<ushort4*>(xs)[(size_t)node * 32 + (i & 31)] =
        *reinterpret_cast<ushort4*>(o);
  }
}

// ======== FUSED: index-broadcast gather (phase 0) + double GEMM + proj ======
// Phase 0 per row: ONE coalesced 64-lane load of edge indices, then srcs come
// from __shfl (no memory dep) -> 4 independent row-gathers per lane in flight.
#define ACC2(A, V)                        \
  A[0] += (f32x2){bflo(V.x), bfhi(V.x)};  \
  A[1] += (f32x2){bflo(V.y), bfhi(V.y)};  \
  A[2] += (f32x2){bflo(V.z), bfhi(V.z)};  \
  A[3] += (f32x2){bflo(V.w), bfhi(V.w)};

__global__ __launch_bounds__(256) void k_fused(
    const char* __restrict__ Gb, const int* __restrict__ offs,
    const int* __restrict__ ebuf, const float* __restrict__ dinv,
    const unsigned short* __restrict__ B1p, const unsigned short* __restrict__ B2p,
    const float* __restrict__ b1, const float* __restrict__ Wl,
    float* __restrict__ P, int n) {
  __shared__ __align__(16) unsigned short sh[32 * 264];  // union z(8KB)/h1
  __shared__ float pacc[32][2];
  int rt0 = blockIdx.x * 2;
  int wave = threadIdx.x >> 6;
  int lane = threadIdx.x & 63;
  int quad = lane >> 4;
  if (threadIdx.x < 64) pacc[threadIdx.x >> 1][threadIdx.x & 1] = 0.f;

  // ---- phase 0: aggregate rows rt0*16 .. rt0*16+31 into sh[0..8KB) ----
  {
    int g = lane >> 4;                 // edge slot 0..3
    int cidx = lane & 15;              // 16B chunk 0..15
    unsigned cb = (unsigned)cidx << 4;
    int rbase = rt0 * 16;
    for (int it = 0; it < 8; ++it) {
      int rin = wave * 8 + it;
      int node = rbase + rin;
      f32x2 acc[4] = {};
      float d = 0.f;
      if (node < n) {
        d = dinv[node];
        int beg = offs[node], end = offs[node + 1];
        int deg = end - beg;
        if (g == 0) {  // self loop: own pre-scaled row
          uint4 s = *reinterpret_cast<const uint4*>(
              Gb + (((unsigned)node << 8) | cb));
          ACC2(acc, s);
        }
        int kb = 0;
        while (kb < deg) {
          int m = min(deg - kb, 64);
          int myi = beg + kb + lane;
          int idx = (myi < end) ? ebuf[myi] : 0;
          int j = 0;
          for (; j + 16 <= m; j += 16) {  // 4 independent gathers in flight
            int s0 = __shfl(idx, j + g);
            int s1 = __shfl(idx, j + 4 + g);
            int s2 = __shfl(idx, j + 8 + g);
            int s3 = __shfl(idx, j + 12 + g);
            uint4 v0 = *reinterpret_cast<const uint4*>(Gb + (((unsigned)s0 << 8) | cb));
            uint4 v1 = *reinterpret_cast<const uint4*>(Gb + (((unsigned)s1 << 8) | cb));
            uint4 v2 = *reinterpret_cast<const uint4*>(Gb + (((unsigned)s2 << 8) | cb));
            uint4 v3 = *reinterpret_cast<const uint4*>(Gb + (((unsigned)s3 << 8) | cb));
            ACC2(acc, v0);
            ACC2(acc, v1);
            ACC2(acc, v2);
            ACC2(acc, v3);
          }
          for (; j + 4 <= m; j += 4) {
            int s0 = __shfl(idx, j + g);
            uint4 v0 = *reinterpret_cast<const uint4*>(Gb + (((unsigned)s0 << 8) | cb));
            ACC2(acc, v0);
          }
          int r = m - j;
          if (r > 0) {  // tail 1..3 edges
            int s0 = __shfl(idx, j + ((g < r) ? g : 0));
            if (g < r) {
              uint4 v0 = *reinterpret_cast<const uint4*>(Gb + (((unsigned)s0 << 8) | cb));
              ACC2(acc, v0);
            }
          }
          kb += 64;
        }
      }
#pragma unroll
      for (int j = 0; j < 4; j++) {  // fold 4 edge-slots into lanes 0..15
        acc[j].x += __shfl_down(acc[j].x, 32);
        acc[j].y += __shfl_down(acc[j].y, 32);
        acc[j].x += __shfl_down(acc[j].x, 16);
        acc[j].y += __shfl_down(acc[j].y, 16);
      }
      if (g == 0) {
        unsigned o[4];
#pragma unroll
        for (int k = 0; k < 4; k++)
          o[k] = (unsigned)f2bf(acc[k].x * d) |
                 ((unsigned)f2bf(acc[k].y * d) << 16);
        *reinterpret_cast<uint4*>(sh + rin * 128 + (cidx ^ (rin & 7)) * 8) =
            *reinterpret_cast<uint4*>(o);
      }
    }
  }
  __syncthreads();

  // ---- phase A prologue: register-stage z fragments, then free the LDS ----
  int r0a = lane & 15;
  int xsw = lane & 7;
  short8 fa0[4], fa1[4];
#pragma unroll
  for (int ks = 0; ks < 4; ks++) {
    int cS = ((quad + ks * 4) ^ xsw) * 8;
    fa0[ks] = *reinterpret_cast<const short8*>(sh + r0a * 128 + cS);
    fa1[ks] = *reinterpret_cast<const short8*>(sh + (16 + r0a) * 128 + cS);
  }
  __syncthreads();

  // ---- phase A: h1 = relu(z@W1+b1), cols wave*64..+63, two 16-row tiles ----
  f32x4 acc[2][4] = {};
#pragma unroll
  for (int ks = 0; ks < 4; ks++) {
#pragma unroll
    for (int ct = 0; ct < 4; ct++) {
      int nt = wave * 4 + ct;
      short8 b = *reinterpret_cast<const short8*>(
          B1p + ((size_t)(nt * 4 + ks) * 64 + lane) * 8);
      acc[0][ct] = __builtin_amdgcn_mfma_f32_16x16x32_bf16(fa0[ks], b, acc[0][ct], 0, 0, 0);
      acc[1][ct] = __builtin_amdgcn_mfma_f32_16x16x32_bf16(fa1[ks], b, acc[1][ct], 0, 0, 0);
    }
  }
#pragma unroll
  for (int ct = 0; ct < 4; ct++) {
    int c = (wave * 4 + ct) * 16 + (lane & 15);
    float bv = b1[c];
#pragma unroll
    for (int rg = 0; rg < 2; rg++)
#pragma unroll
      for (int i = 0; i < 4; i++) {
        float v = fmaxf(acc[rg][ct][i] + bv, 0.f);
        sh[(rg * 16 + quad * 4 + i) * 264 + c] = f2bf(v);
      }
  }
  __syncthreads();

  // ---- phase B: cols wave*32 .. wave*32+31, K=256 from LDS; project to p ----
  f32x4 acc2[2][2] = {};
  const unsigned short* a2_0 = sh + (size_t)(lane & 15) * 264 + quad * 8;
  const unsigned short* a2_1 = sh + (size_t)(16 + (lane & 15)) * 264 + quad * 8;
#pragma unroll
  for (int ks = 0; ks < 8; ks++) {
    short8 a0 = *reinterpret_cast<const short8*>(a2_0 + ks * 32);
    short8 a1 = *reinterpret_cast<const short8*>(a2_1 + ks * 32);
#pragma unroll
    for (int ct = 0; ct < 2; ct++) {
      int nt = wave * 2 + ct;
      short8 b = *reinterpret_cast<const short8*>(
          B2p + ((size_t)(nt * 8 + ks) * 64 + lane) * 8);
      acc2[0][ct] = __builtin_amdgcn_mfma_f32_16x16x32_bf16(a0, b, acc2[0][ct], 0, 0, 0);
      acc2[1][ct] = __builtin_amdgcn_mfma_f32_16x16x32_bf16(a1, b, acc2[1][ct], 0, 0, 0);
    }
  }
  float p1[2][4] = {}, p2[2][4] = {};
#pragma unroll
  for (int rg = 0; rg < 2; rg++) {
    int r0 = (rt0 + rg) * 16 + quad * 4;
    float dv[4];
#pragma unroll
    for (int i = 0; i < 4; i++) dv[i] = dinv[r0 + i];
#pragma unroll
    for (int ct = 0; ct < 2; ct++) {
      int c = (wave * 2 + ct) * 16 + (lane & 15);
      float wl1 = Wl[c], wl2 = Wl[128 + c];
#pragma unroll
      for (int i = 0; i < 4; i++) {
        float v = acc2[rg][ct][i] * dv[i];
        p1[rg][i] = fmaf(v, wl1, p1[rg][i]);
        p2[rg][i] = fmaf(v, wl2, p2[rg][i]);
      }
    }
  }
#pragma unroll
  for (int rg = 0; rg < 2; rg++)
#pragma unroll
    for (int i = 0; i < 4; i++) {
#pragma unroll
      for (int o = 8; o; o >>= 1) {
        p1[rg][i] += __shfl_xor(p1[rg][i], o);
        p2[rg][i] += __shfl_xor(p2[rg][i], o);
      }
    }
  if ((lane & 15) == 0) {
#pragma unroll
    for (int rg = 0; rg < 2; rg++)
#pragma unroll
      for (int i = 0; i < 4; i++) {
        int row = rg * 16 + quad * 4 + i;
        atomicAdd(&pacc[row][0], p1[rg][i]);
        atomicAdd(&pacc[row][1], p2[rg][i]);
      }
  }
  __syncthreads();
  if (threadIdx.x < 64) {
    int row = threadIdx.x >> 1, comp = threadIdx.x & 1;
    P[(size_t)(rt0 * 16 + row) * 2 + comp] = pacc[row][comp];
  }
}

// ---------------- scalar aggregation of projections ----------------
__global__ __launch_bounds__(256) void k_agg_s(const float2* __restrict__ p,
                                               const int* __restrict__ offs,
                                               const int* __restrict__ ebuf,
                                               const float* __restrict__ dinv,
                                               float2* __restrict__ q, int n) {
  int i = blockIdx.x * 64 + (threadIdx.x >> 2);
  if (i >= n) return;
  int sub = threadIdx.x & 3;
  int beg = offs[i], end = offs[i + 1];
  float sx = 0.f, sy = 0.f;
  for (int e = beg + sub; e < end; e += 4) {
    float2 v = p[ebuf[e]];
    sx += v.x;
    sy += v.y;
  }
  sx += __shfl_down(sx, 2);
  sy += __shfl_down(sy, 2);
  sx += __shfl_down(sx, 1);
  sy += __shfl_down(sy, 1);
  if (sub == 0) {
    float2 self = p[i];
    float d = dinv[i];
    q[i] = make_float2((sx + self.x) * d, (sy + self.y) * d);
  }
}

// ---------------- link head: sigmoid(q1[m0] + q2[m1] + C) ----------------
__global__ __launch_bounds__(256) void k_head2(const float2* __restrict__ q,
                                               const int* __restrict__ mask,
                                               const float* __restrict__ Cbuf,
                                               float* __restrict__ out, int P) {
  int p = blockIdx.x * 256 + threadIdx.x;
  if (p >= P) return;
  int m0 = mask[2 * p], m1 = mask[2 * p + 1];
  float s = q[m0].x + q[m1].y + Cbuf[0];
  out[p] = 1.0f / (1.0f + expf(-s));
}

extern "C" void kernel_launch(void* const* d_in, const int* in_sizes, int n_in,
                              void* d_out, int out_size, void* d_ws,
                              size_t ws_size, hipStream_t stream) {
  const int* edge = (const int*)d_in[0];
  const float* feat = (const float*)d_in[1];
  const int* mask = (const int*)d_in[2];
  const float* W1 = (const float*)d_in[3];
  const float* b1 = (const float*)d_in[4];
  const float* W2 = (const float*)d_in[5];
  const float* b2 = (const float*)d_in[6];
  const float* Wl = (const float*)d_in[7];
  const float* bl = (const float*)d_in[8];
  float* out = (float*)d_out;

  const int E = in_sizes[0] / 2;
  const int N = in_sizes[1] / NFEAT;  // must be <= 65536 (16-bit packing)
  const int P = in_sizes[2] / 2;
  const int* rowp = edge;
  const int* colp = edge + E;
  const int nrt = N / 16;             // 3125 for N=50000
  const int nb = (N + 63) / 64;       // 782 buckets (<= 1024 required)
  const int S = nb * NBLK;            // hist entries
  const int nS = (S + 255) / 256;

  auto aln = [](size_t x) { return (x + 255) & ~(size_t)255; };
  char* w = (char*)d_ws;
  int* hist2d = (int*)w;           w += aln((size_t)S * 4);
  int* sbase = (int*)w;            w += aln((size_t)S * 4);
  int* psum = (int*)w;             w += aln((size_t)1024 * 4);
  int* Bq = (int*)w;               w += aln((size_t)1024 * 4);
  float* Cbuf = (float*)w;         w += aln(256);
  int* offs = (int*)w;             w += aln((size_t)(N + 1) * 4);
  int* ebuf = (int*)w;             w += aln((size_t)E * 4);
  unsigned* tmp = (unsigned*)w;    w += aln((size_t)E * 4);
  float* dinv = (float*)w;         w += aln((size_t)N * 4 + 1024);
  unsigned short* xs = (unsigned short*)w;  w += aln((size_t)N * NFEAT * 2);
  float* p = (float*)w;            w += aln((size_t)(N + 32) * 8);
  float2* q = (float2*)w;          w += aln((size_t)N * 8);
  unsigned short* W1p = (unsigned short*)w; w += aln((size_t)NFEAT * NHID * 2);
  unsigned short* W2p = (unsigned short*)w; w += aln((size_t)NHID * NFEAT * 2);

  // ---- CSR build: ONE cooperative kernel (fallback: 5-kernel chain) ----
  {
    int nE_ = E, n_ = N, nb_ = nb;
    void* kb[] = {(void*)&colp, (void*)&rowp, (void*)&hist2d, (void*)&sbase,
                  (void*)&psum, (void*)&Bq,   (void*)&tmp,    (void*)&ebuf,
                  (void*)&offs, (void*)&dinv, (void*)&feat,   (void*)&xs,
                  (void*)&W1,   (void*)&W2,   (void*)&W1p,    (void*)&W2p,
                  (void*)&b2,   (void*)&Wl,   (void*)&bl,     (void*)&Cbuf,
                  (void*)&nE_,  (void*)&n_,   (void*)&nb_};
    hipError_t ce = hipLaunchCooperativeKernel((const void*)k_build,
                                               dim3(NBLK), dim3(1024), kb, 0,
                                               stream);
    if (ce != hipSuccess) {
      (void)hipGetLastError();
      k_hist_pack<<<NBLK + 8, 1024, 0, stream>>>(colp, hist2d, E, nb, W1, W2,
                                                 W1p, W2p);
      k_bsum<<<nS + 1, 256, 0, stream>>>(hist2d, psum, S, b2, Wl, bl, Cbuf);
      k_s3m<<<nS, 256, 0, stream>>>(hist2d, psum, sbase, S);
      k_part2<<<NBLK, 1024, 0, stream>>>(rowp, colp, sbase, tmp, E, nb);
      k_bsort_cvt<<<nb, 256, 0, stream>>>(tmp, sbase, ebuf, offs, dinv, feat,
                                          xs, N, E, nb);
    }
  }
  // fused: per block, aggregate 32 rows (z in LDS only) then
  // p[i] = {(dinv_i*(relu(z@W1+b1)@W2)_i) . Wl_lo, . Wl_hi}
  k_fused<<<(nrt + 1) / 2, 256, 0, stream>>>((const char*)xs, offs, ebuf, dinv,
                                             W1p, W2p, b1, Wl, p, N);
  // q[i] = dinv[i]*(p[i] + sum_in p[src])
  k_agg_s<<<(N + 63) / 64, 256, 0, stream>>>((const float2*)p, offs, ebuf,
                                             dinv, q, N);
  // head: out = sigmoid(q1[m0] + q2[m1] + C)
  k_head2<<<(P + 255) / 256, 256, 0, stream>>>(q, mask, Cbuf, out, P);
}

// Round 6
// 178.972 us; speedup vs baseline: 3.4008x; 3.4008x over previous
//
#include <hip/hip_runtime.h>
#include <math.h>

#define NFEAT 128
#define NHID 256
#define NBLK 256  // partition blocks; (block,bucket) segment avg = 4 edges

typedef __attribute__((ext_vector_type(8))) short short8;
typedef __attribute__((ext_vector_type(4))) float f32x4;
typedef __attribute__((ext_vector_type(2))) float f32x2;

__device__ inline unsigned short f2bf(float f) {
  unsigned u = __float_as_uint(f);
  u += 0x7fffu + ((u >> 16) & 1u);
  return (unsigned short)(u >> 16);
}
__device__ inline float bflo(unsigned u) { return __uint_as_float(u << 16); }
__device__ inline float bfhi(unsigned u) { return __uint_as_float(u & 0xffff0000u); }

// ============ CSR build: deterministic 2-pass partition, no global atomics ==
// bucket = dest >> 6 (64 nodes/bucket); needs N <= 65536 (16-bit packing)

// ---- per-(block,bucket) histogram (blocks 0..NBLK-1) + W-pack (blocks >= NBLK)
__device__ inline void packOne(const float* __restrict__ W,
                               unsigned short* __restrict__ Wp, int idx, int KS,
                               int OUT) {
  int lane = idx & 63;
  int t = idx >> 6;
  int ks = t % KS;
  int nt = t / KS;
  int n = nt * 16 + (lane & 15);
  int k0 = ks * 32 + (lane >> 4) * 8;
  unsigned short v[8];
#pragma unroll
  for (int j = 0; j < 8; j++) v[j] = f2bf(W[(size_t)(k0 + j) * OUT + n]);
  *reinterpret_cast<short8*>(Wp + (size_t)idx * 8) =
      *reinterpret_cast<short8*>(v);
}

__global__ __launch_bounds__(1024) void k_hist_pack(
    const int* __restrict__ col, int* __restrict__ hist2d, int nE, int nb,
    const float* __restrict__ W1, const float* __restrict__ W2,
    unsigned short* __restrict__ W1p, unsigned short* __restrict__ W2p) {
  if (blockIdx.x >= NBLK) {  // pack blocks: 8 x 1024 threads = 8192 items
    int idx = (blockIdx.x - NBLK) * 1024 + threadIdx.x;
    if (idx < 4096) packOne(W1, W1p, idx, 4, 256);
    else packOne(W2, W2p, idx - 4096, 8, 128);
    return;
  }
  __shared__ int h[1024];
  for (int i = threadIdx.x; i < nb; i += 1024) h[i] = 0;
  __syncthreads();
  int chunk = (nE + NBLK - 1) / NBLK;
  int beg = blockIdx.x * chunk, end = min(beg + chunk, nE);
  for (int e = beg + threadIdx.x; e < end; e += 1024)
    atomicAdd(&h[col[e] >> 6], 1);
  __syncthreads();
  for (int i = threadIdx.x; i < nb; i += 1024)
    hist2d[i * NBLK + blockIdx.x] = h[i];
}

// ---- scan phase 1: per-256-chunk sums; last block computes head constant ----
__global__ __launch_bounds__(256) void k_bsum(const int* __restrict__ a,
                                              int* __restrict__ psum, int S,
                                              const float* __restrict__ b2,
                                              const float* __restrict__ Wl,
                                              const float* __restrict__ bl,
                                              float* __restrict__ Cbuf) {
  int t = threadIdx.x;
  if (blockIdx.x == gridDim.x - 1) {  // C = b2.(Wl_lo+Wl_hi) + bl
    float v = (t < 128) ? b2[t] * (Wl[t] + Wl[128 + t]) : 0.f;
#pragma unroll
    for (int o = 32; o; o >>= 1) v += __shfl_down(v, o);
    __shared__ float fw[4];
    if ((t & 63) == 0) fw[t >> 6] = v;
    __syncthreads();
    if (t == 0) Cbuf[0] = fw[0] + fw[1] + fw[2] + fw[3] + bl[0];
    return;
  }
  int i = blockIdx.x * 256 + t;
  int v = (i < S) ? a[i] : 0;
#pragma unroll
  for (int o = 32; o; o >>= 1) v += __shfl_down(v, o);
  __shared__ int ws[4];
  if ((t & 63) == 0) ws[t >> 6] = v;
  __syncthreads();
  if (t == 0) psum[blockIdx.x] = ws[0] + ws[1] + ws[2] + ws[3];
}

// ---- scan phase 2+3 merged: each block redundantly reduces psum[0..b) for
//      its base, then scans its own 256 elements ----
__global__ __launch_bounds__(256) void k_s3m(const int* __restrict__ a,
                                             const int* __restrict__ psum,
                                             int* __restrict__ out, int S) {
  __shared__ int sh[256];
  __shared__ int ws[4];
  int t = threadIdx.x;
  int b = blockIdx.x;
  int partial = 0;
  for (int i = t; i < b; i += 256) partial += psum[i];
#pragma unroll
  for (int o = 32; o; o >>= 1) partial += __shfl_down(partial, o);
  if ((t & 63) == 0) ws[t >> 6] = partial;
  int i = b * 256 + t;
  int d = (i < S) ? a[i] : 0;
  sh[t] = d;
  __syncthreads();
  int base = ws[0] + ws[1] + ws[2] + ws[3];
  for (int o = 1; o < 256; o <<= 1) {
    int u = (t >= o) ? sh[t - o] : 0;
    __syncthreads();
    sh[t] += u;
    __syncthreads();
  }
  if (i < S) out[i] = base + sh[t] - d;
}

// ---- partition: each block writes its own contiguous segments ----
__global__ __launch_bounds__(1024) void k_part2(const int* __restrict__ row,
                                                const int* __restrict__ col,
                                                const int* __restrict__ sbase,
                                                unsigned* __restrict__ tmp,
                                                int nE, int nb) {
  __shared__ int cur[1024];
  for (int i = threadIdx.x; i < nb; i += 1024)
    cur[i] = sbase[i * NBLK + blockIdx.x];
  __syncthreads();
  int chunk = (nE + NBLK - 1) / NBLK;
  int beg = blockIdx.x * chunk, end = min(beg + chunk, nE);
  for (int e = beg + threadIdx.x; e < end; e += 1024) {
    int c = col[e];
    int pos = atomicAdd(&cur[c >> 6], 1);
    tmp[pos] = ((unsigned)(c & 63) << 16) | (unsigned)row[e];
  }
}

// ---- per-bucket counting sort -> ebuf + offs + dinv; also cvt this bucket's
//      64 feature rows: xs = bf16(dinv[row] * X). Per-wave privatized bins. --
__global__ __launch_bounds__(256) void k_bsort_cvt(
    const unsigned* __restrict__ tmp, const int* __restrict__ sbase,
    int* __restrict__ ebuf, int* __restrict__ offs, float* __restrict__ dinv,
    const float* __restrict__ feat, unsigned short* __restrict__ xs, int n,
    int nE, int nb) {
  __shared__ int bins[4][64], cur4[4][64];
  __shared__ float sdinv[64];
  int b = blockIdx.x;
  int beg = sbase[b * NBLK];
  int end = (b == nb - 1) ? nE : sbase[(b + 1) * NBLK];
  int t = threadIdx.x;
  int w4 = t >> 6;
  if (t == 0 && b == nb - 1) offs[n] = nE;
  bins[w4][t & 63] = 0;
  __syncthreads();
  for (int i = beg + t; i < end; i += 256)
    atomicAdd(&bins[w4][tmp[i] >> 16], 1);
  __syncthreads();
  if (t < 64) {  // wave 0: exclusive scan of 64 bucket totals via shfl
    int b0 = bins[0][t], b1 = bins[1][t], b2 = bins[2][t], b3 = bins[3][t];
    int v = b0 + b1 + b2 + b3;
    int s = v;
#pragma unroll
    for (int o = 1; o < 64; o <<= 1) {
      int u = __shfl_up(s, o);
      if (t >= o) s += u;
    }
    int off = beg + s - v;
    cur4[0][t] = off;
    cur4[1][t] = off + b0;
    cur4[2][t] = off + b0 + b1;
    cur4[3][t] = off + b0 + b1 + b2;
    float dv = rsqrtf((float)(v + 1));  // +1 self loop
    sdinv[t] = dv;
    int node = b * 64 + t;
    if (node < n) {
      offs[node] = off;
      dinv[node] = dv;
    }
  }
  __syncthreads();
  for (int i = beg + t; i < end; i += 256) {
    unsigned p = tmp[i];
    int pos = atomicAdd(&cur4[w4][p >> 16], 1);
    ebuf[pos] = (int)(p & 0xffffu);
  }
  // cvt: 64 rows x 32 float4
  for (int i = t; i < 64 * 32; i += 256) {
    int r = i >> 5;
    int node = b * 64 + r;
    if (node >= n) break;
    float d = sdinv[r];
    float4 v = reinterpret_cast<const float4*>(feat)[(size_t)node * 32 + (i & 31)];
    unsigned short o[4] = {f2bf(v.x * d), f2bf(v.y * d), f2bf(v.z * d),
                           f2bf(v.w * d)};
    reinterpret_cast<ushort4*>(xs)[(size_t)node * 32 + (i & 31)] =
        *reinterpret_cast<ushort4*>(o);
  }
}

// ======== FUSED: index-broadcast gather (phase 0) + double GEMM + proj ======
// Phase 0 per row: ONE coalesced 64-lane load of edge indices, then srcs come
// from __shfl (no memory dep) -> 4 independent row-gathers per lane in flight.
#define ACC2(A, V)                        \
  A[0] += (f32x2){bflo(V.x), bfhi(V.x)};  \
  A[1] += (f32x2){bflo(V.y), bfhi(V.y)};  \
  A[2] += (f32x2){bflo(V.z), bfhi(V.z)};  \
  A[3] += (f32x2){bflo(V.w), bfhi(V.w)};

__global__ __launch_bounds__(256) void k_fused(
    const char* __restrict__ Gb, const int* __restrict__ offs,
    const int* __restrict__ ebuf, const float* __restrict__ dinv,
    const unsigned short* __restrict__ B1p, const unsigned short* __restrict__ B2p,
    const float* __restrict__ b1, const float* __restrict__ Wl,
    float* __restrict__ P, int n) {
  __shared__ __align__(16) unsigned short sh[32 * 264];  // union z(8KB)/h1
  __shared__ float pacc[32][2];
  int rt0 = blockIdx.x * 2;
  int wave = threadIdx.x >> 6;
  int lane = threadIdx.x & 63;
  int quad = lane >> 4;
  if (threadIdx.x < 64) pacc[threadIdx.x >> 1][threadIdx.x & 1] = 0.f;

  // ---- phase 0: aggregate rows rt0*16 .. rt0*16+31 into sh[0..8KB) ----
  {
    int g = lane >> 4;                 // edge slot 0..3
    int cidx = lane & 15;              // 16B chunk 0..15
    unsigned cb = (unsigned)cidx << 4;
    int rbase = rt0 * 16;
    for (int it = 0; it < 8; ++it) {
      int rin = wave * 8 + it;
      int node = rbase + rin;
      f32x2 acc[4] = {};
      float d = 0.f;
      if (node < n) {
        d = dinv[node];
        int beg = offs[node], end = offs[node + 1];
        int deg = end - beg;
        if (g == 0) {  // self loop: own pre-scaled row
          uint4 s = *reinterpret_cast<const uint4*>(
              Gb + (((unsigned)node << 8) | cb));
          ACC2(acc, s);
        }
        int kb = 0;
        while (kb < deg) {
          int m = min(deg - kb, 64);
          int myi = beg + kb + lane;
          int idx = (myi < end) ? ebuf[myi] : 0;
          int j = 0;
          for (; j + 16 <= m; j += 16) {  // 4 independent gathers in flight
            int s0 = __shfl(idx, j + g);
            int s1 = __shfl(idx, j + 4 + g);
            int s2 = __shfl(idx, j + 8 + g);
            int s3 = __shfl(idx, j + 12 + g);
            uint4 v0 = *reinterpret_cast<const uint4*>(Gb + (((unsigned)s0 << 8) | cb));
            uint4 v1 = *reinterpret_cast<const uint4*>(Gb + (((unsigned)s1 << 8) | cb));
            uint4 v2 = *reinterpret_cast<const uint4*>(Gb + (((unsigned)s2 << 8) | cb));
            uint4 v3 = *reinterpret_cast<const uint4*>(Gb + (((unsigned)s3 << 8) | cb));
            ACC2(acc, v0);
            ACC2(acc, v1);
            ACC2(acc, v2);
            ACC2(acc, v3);
          }
          for (; j + 4 <= m; j += 4) {
            int s0 = __shfl(idx, j + g);
            uint4 v0 = *reinterpret_cast<const uint4*>(Gb + (((unsigned)s0 << 8) | cb));
            ACC2(acc, v0);
          }
          int r = m - j;
          if (r > 0) {  // tail 1..3 edges
            int s0 = __shfl(idx, j + ((g < r) ? g : 0));
            if (g < r) {
              uint4 v0 = *reinterpret_cast<const uint4*>(Gb + (((unsigned)s0 << 8) | cb));
              ACC2(acc, v0);
            }
          }
          kb += 64;
        }
      }
#pragma unroll
      for (int j = 0; j < 4; j++) {  // fold 4 edge-slots into lanes 0..15
        acc[j].x += __shfl_down(acc[j].x, 32);
        acc[j].y += __shfl_down(acc[j].y, 32);
        acc[j].x += __shfl_down(acc[j].x, 16);
        acc[j].y += __shfl_down(acc[j].y, 16);
      }
      if (g == 0) {
        unsigned o[4];
#pragma unroll
        for (int k = 0; k < 4; k++)
          o[k] = (unsigned)f2bf(acc[k].x * d) |
                 ((unsigned)f2bf(acc[k].y * d) << 16);
        *reinterpret_cast<uint4*>(sh + rin * 128 + (cidx ^ (rin & 7)) * 8) =
            *reinterpret_cast<uint4*>(o);
      }
    }
  }
  __syncthreads();

  // ---- phase A prologue: register-stage z fragments, then free the LDS ----
  int r0a = lane & 15;
  int xsw = lane & 7;
  short8 fa0[4], fa1[4];
#pragma unroll
  for (int ks = 0; ks < 4; ks++) {
    int cS = ((quad + ks * 4) ^ xsw) * 8;
    fa0[ks] = *reinterpret_cast<const short8*>(sh + r0a * 128 + cS);
    fa1[ks] = *reinterpret_cast<const short8*>(sh + (16 + r0a) * 128 + cS);
  }
  __syncthreads();

  // ---- phase A: h1 = relu(z@W1+b1), cols wave*64..+63, two 16-row tiles ----
  f32x4 acc[2][4] = {};
#pragma unroll
  for (int ks = 0; ks < 4; ks++) {
#pragma unroll
    for (int ct = 0; ct < 4; ct++) {
      int nt = wave * 4 + ct;
      short8 b = *reinterpret_cast<const short8*>(
          B1p + ((size_t)(nt * 4 + ks) * 64 + lane) * 8);
      acc[0][ct] = __builtin_amdgcn_mfma_f32_16x16x32_bf16(fa0[ks], b, acc[0][ct], 0, 0, 0);
      acc[1][ct] = __builtin_amdgcn_mfma_f32_16x16x32_bf16(fa1[ks], b, acc[1][ct], 0, 0, 0);
    }
  }
#pragma unroll
  for (int ct = 0; ct < 4; ct++) {
    int c = (wave * 4 + ct) * 16 + (lane & 15);
    float bv = b1[c];
#pragma unroll
    for (int rg = 0; rg < 2; rg++)
#pragma unroll
      for (int i = 0; i < 4; i++) {
        float v = fmaxf(acc[rg][ct][i] + bv, 0.f);
        sh[(rg * 16 + quad * 4 + i) * 264 + c] = f2bf(v);
      }
  }
  __syncthreads();

  // ---- phase B: cols wave*32 .. wave*32+31, K=256 from LDS; project to p ----
  f32x4 acc2[2][2] = {};
  const unsigned short* a2_0 = sh + (size_t)(lane & 15) * 264 + quad * 8;
  const unsigned short* a2_1 = sh + (size_t)(16 + (lane & 15)) * 264 + quad * 8;
#pragma unroll
  for (int ks = 0; ks < 8; ks++) {
    short8 a0 = *reinterpret_cast<const short8*>(a2_0 + ks * 32);
    short8 a1 = *reinterpret_cast<const short8*>(a2_1 + ks * 32);
#pragma unroll
    for (int ct = 0; ct < 2; ct++) {
      int nt = wave * 2 + ct;
      short8 b = *reinterpret_cast<const short8*>(
          B2p + ((size_t)(nt * 8 + ks) * 64 + lane) * 8);
      acc2[0][ct] = __builtin_amdgcn_mfma_f32_16x16x32_bf16(a0, b, acc2[0][ct], 0, 0, 0);
      acc2[1][ct] = __builtin_amdgcn_mfma_f32_16x16x32_bf16(a1, b, acc2[1][ct], 0, 0, 0);
    }
  }
  float p1[2][4] = {}, p2[2][4] = {};
#pragma unroll
  for (int rg = 0; rg < 2; rg++) {
    int r0 = (rt0 + rg) * 16 + quad * 4;
    float dv[4];
#pragma unroll
    for (int i = 0; i < 4; i++) dv[i] = dinv[r0 + i];
#pragma unroll
    for (int ct = 0; ct < 2; ct++) {
      int c = (wave * 2 + ct) * 16 + (lane & 15);
      float wl1 = Wl[c], wl2 = Wl[128 + c];
#pragma unroll
      for (int i = 0; i < 4; i++) {
        float v = acc2[rg][ct][i] * dv[i];
        p1[rg][i] = fmaf(v, wl1, p1[rg][i]);
        p2[rg][i] = fmaf(v, wl2, p2[rg][i]);
      }
    }
  }
#pragma unroll
  for (int rg = 0; rg < 2; rg++)
#pragma unroll
    for (int i = 0; i < 4; i++) {
#pragma unroll
      for (int o = 8; o; o >>= 1) {
        p1[rg][i] += __shfl_xor(p1[rg][i], o);
        p2[rg][i] += __shfl_xor(p2[rg][i], o);
      }
    }
  if ((lane & 15) == 0) {
#pragma unroll
    for (int rg = 0; rg < 2; rg++)
#pragma unroll
      for (int i = 0; i < 4; i++) {
        int row = rg * 16 + quad * 4 + i;
        atomicAdd(&pacc[row][0], p1[rg][i]);
        atomicAdd(&pacc[row][1], p2[rg][i]);
      }
  }
  __syncthreads();
  if (threadIdx.x < 64) {
    int row = threadIdx.x >> 1, comp = threadIdx.x & 1;
    P[(size_t)(rt0 * 16 + row) * 2 + comp] = pacc[row][comp];
  }
}

// ---------------- scalar aggregation of projections ----------------
// 4 lanes per node (64 nodes/block): q[i] = dinv[i]*(p[i] + sum_in p[src])
__global__ __launch_bounds__(256) void k_agg_s(const float2* __restrict__ p,
                                               const int* __restrict__ offs,
                                               const int* __restrict__ ebuf,
                                               const float* __restrict__ dinv,
                                               float2* __restrict__ q, int n) {
  int i = blockIdx.x * 64 + (threadIdx.x >> 2);
  if (i >= n) return;
  int sub = threadIdx.x & 3;
  int beg = offs[i], end = offs[i + 1];
  float sx = 0.f, sy = 0.f;
  for (int e = beg + sub; e < end; e += 4) {
    float2 v = p[ebuf[e]];
    sx += v.x;
    sy += v.y;
  }
  sx += __shfl_down(sx, 2);
  sy += __shfl_down(sy, 2);
  sx += __shfl_down(sx, 1);
  sy += __shfl_down(sy, 1);
  if (sub == 0) {
    float2 self = p[i];
    float d = dinv[i];
    q[i] = make_float2((sx + self.x) * d, (sy + self.y) * d);
  }
}

// ---------------- link head: sigmoid(q1[m0] + q2[m1] + C) ----------------
__global__ __launch_bounds__(256) void k_head2(const float2* __restrict__ q,
                                               const int* __restrict__ mask,
                                               const float* __restrict__ Cbuf,
                                               float* __restrict__ out, int P) {
  int p = blockIdx.x * 256 + threadIdx.x;
  if (p >= P) return;
  int m0 = mask[2 * p], m1 = mask[2 * p + 1];
  float s = q[m0].x + q[m1].y + Cbuf[0];
  out[p] = 1.0f / (1.0f + expf(-s));
}

extern "C" void kernel_launch(void* const* d_in, const int* in_sizes, int n_in,
                              void* d_out, int out_size, void* d_ws,
                              size_t ws_size, hipStream_t stream) {
  const int* edge = (const int*)d_in[0];
  const float* feat = (const float*)d_in[1];
  const int* mask = (const int*)d_in[2];
  const float* W1 = (const float*)d_in[3];
  const float* b1 = (const float*)d_in[4];
  const float* W2 = (const float*)d_in[5];
  const float* b2 = (const float*)d_in[6];
  const float* Wl = (const float*)d_in[7];
  const float* bl = (const float*)d_in[8];
  float* out = (float*)d_out;

  const int E = in_sizes[0] / 2;
  const int N = in_sizes[1] / NFEAT;  // must be <= 65536 (16-bit packing)
  const int P = in_sizes[2] / 2;
  const int* rowp = edge;
  const int* colp = edge + E;
  const int nrt = N / 16;             // 3125 for N=50000
  const int nb = (N + 63) / 64;       // 782 buckets (<= 1024 required)
  const int S = nb * NBLK;            // 200192 hist entries
  const int nS = (S + 255) / 256;     // 782 scan chunks (<= 1024 required)

  auto aln = [](size_t x) { return (x + 255) & ~(size_t)255; };
  char* w = (char*)d_ws;
  int* hist2d = (int*)w;           w += aln((size_t)S * 4);
  int* sbase = (int*)w;            w += aln((size_t)S * 4);
  int* psum = (int*)w;             w += aln((size_t)1024 * 4);
  float* Cbuf = (float*)w;         w += aln(256);
  int* offs = (int*)w;             w += aln((size_t)(N + 1) * 4);
  int* ebuf = (int*)w;             w += aln((size_t)E * 4);
  unsigned* tmp = (unsigned*)w;    w += aln((size_t)E * 4);
  float* dinv = (float*)w;         w += aln((size_t)N * 4 + 1024);
  unsigned short* xs = (unsigned short*)w;  w += aln((size_t)N * NFEAT * 2);
  float* p = (float*)w;            w += aln((size_t)(N + 32) * 8);
  float2* q = (float2*)w;          w += aln((size_t)N * 8);
  unsigned short* W1p = (unsigned short*)w; w += aln((size_t)NFEAT * NHID * 2);
  unsigned short* W2p = (unsigned short*)w; w += aln((size_t)NHID * NFEAT * 2);

  // ---- CSR build: deterministic 2-pass partition (+ W pack on spare blocks)
  k_hist_pack<<<NBLK + 8, 1024, 0, stream>>>(colp, hist2d, E, nb, W1, W2, W1p,
                                             W2p);
  k_bsum<<<nS + 1, 256, 0, stream>>>(hist2d, psum, S, b2, Wl, bl, Cbuf);
  k_s3m<<<nS, 256, 0, stream>>>(hist2d, psum, sbase, S);
  k_part2<<<NBLK, 1024, 0, stream>>>(rowp, colp, sbase, tmp, E, nb);
  // bsort + per-bucket cvt: ebuf/offs/dinv + xs = bf16(dinv * X)
  k_bsort_cvt<<<nb, 256, 0, stream>>>(tmp, sbase, ebuf, offs, dinv, feat, xs,
                                      N, E, nb);
  // fused: per block, aggregate 32 rows (z in LDS only) then
  // p[i] = {(dinv_i*(relu(z@W1+b1)@W2)_i) . Wl_lo, . Wl_hi}
  k_fused<<<(nrt + 1) / 2, 256, 0, stream>>>((const char*)xs, offs, ebuf, dinv,
                                             W1p, W2p, b1, Wl, p, N);
  // q[i] = dinv[i]*(p[i] + sum_in p[src])
  k_agg_s<<<(N + 63) / 64, 256, 0, stream>>>((const float2*)p, offs, ebuf,
                                             dinv, q, N);
  // head: out = sigmoid(q1[m0] + q2[m1] + C)
  k_head2<<<(P + 255) / 256, 256, 0, stream>>>(q, mask, Cbuf, out, P);
}